// Round 6
// baseline (43.241 us; speedup 1.0000x reference)
//
#include <hip/hip_runtime.h>
#include <math.h>

#define BLK 100          // BLOCK
#define NF  128          // N_freqs
#define NTOT (NF * BLK)  // 12800
#define P   104          // LDS pitch (floats): rows 16B-aligned (416B); row-to-row bank shift = 8

__device__ __forceinline__ float4 fnma4(float4 v, float s, const float4 p) {
    v.x -= s * p.x; v.y -= s * p.y; v.z -= s * p.z; v.w -= s * p.w; return v;
}

#define LD4(r, c4) (*reinterpret_cast<float4*>(&a[(r) * P + 4 * (c4)]))

// One workgroup per frequency block. Rank-4 blocked non-pivoted LU, ONE
// barrier per phase, NO specialized panel wave: every lane redundantly
// factors the 4x4 panel in registers from the broadcast panel column group
// (pp0..pp3) -- pure scalar chain, no readlane, no pivot-row LDS writes.
// Pivot rows k0..k0+3 are never written back (dead after the phase); their
// updated values live in regs (pp*, P*) and feed the sweep directly.
// logdet accumulates redundantly in every thread; thread 0 writes + atomics.
__global__ __launch_bounds__(256) void lu_logdet_kernel(const float* __restrict__ w,
                                                        const float* __restrict__ L,
                                                        float* __restrict__ out) {
    __shared__ float a[BLK * P];

    const int f   = blockIdx.x;
    const int tid = threadIdx.x;
    const int sid = tid >> 5;        // 8 half-wave streams
    const int g   = tid & 31;        // float4 column group
    const int gg  = (g < 25) ? g : 24;   // clamped: keeps inactive lanes in-bounds, branch-free

    // ---- load diag block f, fused transform: M[r][c] = s_r*D[r][c] + (r==c ? 1-s_r : 0)
    const float* base = L + (size_t)f * BLK * NTOT + (size_t)f * BLK;
    for (int q = tid; q < BLK * 25; q += 256) {        // 25 float4 per row
        const int r  = q / 25;
        const int c0 = (q - r * 25) * 4;
        const float4 v = *reinterpret_cast<const float4*>(base + (size_t)r * NTOT + c0);
        const float sv = 1.0f / (1.0f + expf(-w[f * BLK + r]));
        const float ds = 1.0f - sv;
        float4 m;
        m.x = sv * v.x + ((c0 + 0) == r ? ds : 0.0f);
        m.y = sv * v.y + ((c0 + 1) == r ? ds : 0.0f);
        m.z = sv * v.z + ((c0 + 2) == r ? ds : 0.0f);
        m.w = sv * v.w + ((c0 + 3) == r ? ds : 0.0f);
        *reinterpret_cast<float4*>(&a[r * P + c0]) = m;
    }
    __syncthreads();

    float lsum = 0.0f;
    int   lneg = 0;

    for (int k0 = 0; k0 < BLK; k0 += 4) {
        const int gp = k0 >> 2;

        // ---- redundant in-register panel factorization (no cross-lane ops)
        float4 pp0 = LD4(k0 + 0, gp);    // broadcast reads (uniform addr)
        float4 pp1 = LD4(k0 + 1, gp);
        float4 pp2 = LD4(k0 + 2, gp);
        float4 pp3 = LD4(k0 + 3, gp);
        float4 P0  = LD4(k0 + 0, gg);    // this lane's column group of pivot rows
        float4 P1  = LD4(k0 + 1, gg);
        float4 P2  = LD4(k0 + 2, gg);
        float4 P3  = LD4(k0 + 3, gg);

        const float d0 = pp0.x, r0i = 1.0f / d0;
        float fc;
        fc = pp1.x * r0i;  pp1 = fnma4(pp1, fc, pp0);  P1 = fnma4(P1, fc, P0);
        const float d1 = pp1.y, r1i = 1.0f / d1;
        fc = pp2.x * r0i;  pp2 = fnma4(pp2, fc, pp0);  P2 = fnma4(P2, fc, P0);
        fc = pp2.y * r1i;  pp2 = fnma4(pp2, fc, pp1);  P2 = fnma4(P2, fc, P1);
        const float d2 = pp2.z, r2i = 1.0f / d2;
        fc = pp3.x * r0i;  pp3 = fnma4(pp3, fc, pp0);  P3 = fnma4(P3, fc, P0);
        fc = pp3.y * r1i;  pp3 = fnma4(pp3, fc, pp1);  P3 = fnma4(P3, fc, P1);
        fc = pp3.z * r2i;  pp3 = fnma4(pp3, fc, pp2);  P3 = fnma4(P3, fc, P2);
        const float d3 = pp3.w, r3i = 1.0f / d3;

        lsum += logf(fabsf(d0)) + logf(fabsf(d1)) + logf(fabsf(d2)) + logf(fabsf(d3));
        lneg += (d0 < 0.0f) + (d1 < 0.0f) + (d2 < 0.0f) + (d3 < 0.0f);

        // ---- sweep: rank-4 update of rows k0+4..99, 8 streams, groups > gp
#define FACS(pan, f0, f1, f2, f3)                                             \
        const float f0 = pan.x * r0i;                                         \
        const float f1 = (pan.y - f0 * pp0.y) * r1i;                          \
        const float f2 = (pan.z - f0 * pp0.z - f1 * pp1.z) * r2i;             \
        const float f3 = (pan.w - f0 * pp0.w - f1 * pp1.w - f2 * pp2.w) * r3i;

        if (g > gp && g < 25) {
            int i = k0 + 4 + sid;
            for (; i + 8 < BLK; i += 16) {
                const int i2 = i + 8;
                const float4 panA = LD4(i,  gp);
                const float4 panB = LD4(i2, gp);
                float4 vA = LD4(i,  g);
                float4 vB = LD4(i2, g);
                FACS(panA, a0, a1, a2, a3)
                FACS(panB, b0, b1, b2, b3)
                vA = fnma4(vA, a0, P0); vA = fnma4(vA, a1, P1);
                vA = fnma4(vA, a2, P2); vA = fnma4(vA, a3, P3);
                vB = fnma4(vB, b0, P0); vB = fnma4(vB, b1, P1);
                vB = fnma4(vB, b2, P2); vB = fnma4(vB, b3, P3);
                LD4(i,  g) = vA;
                LD4(i2, g) = vB;
            }
            for (; i < BLK; i += 8) {
                const float4 pan = LD4(i, gp);
                float4 v = LD4(i, g);
                FACS(pan, c0, c1, c2, c3)
                v = fnma4(v, c0, P0); v = fnma4(v, c1, P1);
                v = fnma4(v, c2, P2); v = fnma4(v, c3, P3);
                LD4(i, g) = v;
            }
        }
#undef FACS
        __syncthreads();
    }

    // ---- every thread holds the full logdet redundantly; thread 0 publishes
    if (tid == 0) {
        float ld = lsum;
        if ((lneg & 1) || !isfinite(ld)) ld = __int_as_float(0x7fc00000);  // NaN
        out[1 + f] = ld;
        atomicAdd(out, ld);   // out[0] zeroed via memset before launch; NaN propagates
    }
}

extern "C" void kernel_launch(void* const* d_in, const int* in_sizes, int n_in,
                              void* d_out, int out_size, void* d_ws, size_t ws_size,
                              hipStream_t stream) {
    const float* w = (const float*)d_in[0];   // weights (12800,) f32
    const float* L = (const float*)d_in[1];   // L_kernel (12800,12800) f32
    float* out = (float*)d_out;               // [0]=sum, [1..128]=logdets
    hipMemsetAsync(d_out, 0, sizeof(float), stream);   // zero the atomic accumulator
    lu_logdet_kernel<<<NF, 256, 0, stream>>>(w, L, out);
}

// Round 7
// 35.640 us; speedup vs baseline: 1.2133x; 1.2133x over previous
//
#include <hip/hip_runtime.h>
#include <math.h>

#define BLK 100          // BLOCK
#define NF  128          // N_freqs
#define NTOT (NF * BLK)  // 12800
#define P   104          // LDS pitch (floats): rows 16B-aligned (416B)
#define NT  512          // threads: 8 waves = 2 waves/SIMD -> TLP hides chains

__device__ __forceinline__ float4 fnma4(float4 v, float s, const float4 p) {
    v.x -= s * p.x; v.y -= s * p.y; v.z -= s * p.z; v.w -= s * p.w; return v;
}

#define LD4(r, c4) (*reinterpret_cast<float4*>(&a[(r) * P + 4 * (c4)]))

// One workgroup (512 thr) per frequency block. Rank-4 blocked non-pivoted LU,
// ONE barrier per phase. Every lane redundantly factors the 4x4 panel in
// registers from the broadcast panel column group (no cross-lane ops, no
// pivot-row writeback). With 2 waves/SIMD the panel chain and LDS latency
// hide under the co-resident wave's sweep. diag -> LDS (thread 0, 4 scalar
// writes/phase); logf done once, in parallel, in the epilogue.
__global__ __launch_bounds__(NT) void lu_logdet_kernel(const float* __restrict__ w,
                                                       const float* __restrict__ L,
                                                       float* __restrict__ out) {
    __shared__ float a[BLK * P];
    __shared__ float diag[BLK];
    __shared__ float ps[2];
    __shared__ int   pn[2];

    const int f   = blockIdx.x;
    const int tid = threadIdx.x;
    const int sid = tid >> 5;        // 16 half-wave streams
    const int g   = tid & 31;        // float4 column group
    const int gg  = (g < 25) ? g : 24;   // clamped, keeps inactive lanes in-bounds

    // ---- load diag block f, fused transform: M[r][c] = s_r*D[r][c] + (r==c ? 1-s_r : 0)
    const float* base = L + (size_t)f * BLK * NTOT + (size_t)f * BLK;
    for (int q = tid; q < BLK * 25; q += NT) {         // 25 float4 per row
        const int r  = q / 25;
        const int c0 = (q - r * 25) * 4;
        const float4 v = *reinterpret_cast<const float4*>(base + (size_t)r * NTOT + c0);
        const float sv = 1.0f / (1.0f + expf(-w[f * BLK + r]));
        const float ds = 1.0f - sv;
        float4 m;
        m.x = sv * v.x + ((c0 + 0) == r ? ds : 0.0f);
        m.y = sv * v.y + ((c0 + 1) == r ? ds : 0.0f);
        m.z = sv * v.z + ((c0 + 2) == r ? ds : 0.0f);
        m.w = sv * v.w + ((c0 + 3) == r ? ds : 0.0f);
        *reinterpret_cast<float4*>(&a[r * P + c0]) = m;
    }
    __syncthreads();

    for (int k0 = 0; k0 < BLK; k0 += 4) {
        const int gp = k0 >> 2;

        // ---- redundant in-register panel factorization (no cross-lane ops)
        float4 pp0 = LD4(k0 + 0, gp);    // broadcast reads (uniform addr)
        float4 pp1 = LD4(k0 + 1, gp);
        float4 pp2 = LD4(k0 + 2, gp);
        float4 pp3 = LD4(k0 + 3, gp);
        float4 P0  = LD4(k0 + 0, gg);    // this lane's column group of pivot rows
        float4 P1  = LD4(k0 + 1, gg);
        float4 P2  = LD4(k0 + 2, gg);
        float4 P3  = LD4(k0 + 3, gg);

        const float d0 = pp0.x, r0i = 1.0f / d0;
        float fc;
        fc = pp1.x * r0i;  pp1 = fnma4(pp1, fc, pp0);  P1 = fnma4(P1, fc, P0);
        const float d1 = pp1.y, r1i = 1.0f / d1;
        fc = pp2.x * r0i;  pp2 = fnma4(pp2, fc, pp0);  P2 = fnma4(P2, fc, P0);
        fc = pp2.y * r1i;  pp2 = fnma4(pp2, fc, pp1);  P2 = fnma4(P2, fc, P1);
        const float d2 = pp2.z, r2i = 1.0f / d2;
        fc = pp3.x * r0i;  pp3 = fnma4(pp3, fc, pp0);  P3 = fnma4(P3, fc, P0);
        fc = pp3.y * r1i;  pp3 = fnma4(pp3, fc, pp1);  P3 = fnma4(P3, fc, P1);
        fc = pp3.z * r2i;  pp3 = fnma4(pp3, fc, pp2);  P3 = fnma4(P3, fc, P2);
        const float d3 = pp3.w, r3i = 1.0f / d3;

        if (tid == 0) {
            diag[k0 + 0] = d0; diag[k0 + 1] = d1;
            diag[k0 + 2] = d2; diag[k0 + 3] = d3;
        }

        // ---- sweep: rank-4 update of rows k0+4..99, 16 streams, groups > gp
#define FACS(pan, f0, f1, f2, f3)                                             \
        const float f0 = pan.x * r0i;                                         \
        const float f1 = (pan.y - f0 * pp0.y) * r1i;                          \
        const float f2 = (pan.z - f0 * pp0.z - f1 * pp1.z) * r2i;             \
        const float f3 = (pan.w - f0 * pp0.w - f1 * pp1.w - f2 * pp2.w) * r3i;

        if (g > gp && g < 25) {
            int i = k0 + 4 + sid;
            for (; i + 16 < BLK; i += 32) {
                const int i2 = i + 16;
                const float4 panA = LD4(i,  gp);
                const float4 panB = LD4(i2, gp);
                float4 vA = LD4(i,  g);
                float4 vB = LD4(i2, g);
                FACS(panA, a0, a1, a2, a3)
                FACS(panB, b0, b1, b2, b3)
                vA = fnma4(vA, a0, P0); vA = fnma4(vA, a1, P1);
                vA = fnma4(vA, a2, P2); vA = fnma4(vA, a3, P3);
                vB = fnma4(vB, b0, P0); vB = fnma4(vB, b1, P1);
                vB = fnma4(vB, b2, P2); vB = fnma4(vB, b3, P3);
                LD4(i,  g) = vA;
                LD4(i2, g) = vB;
            }
            for (; i < BLK; i += 16) {
                const float4 pan = LD4(i, gp);
                float4 v = LD4(i, g);
                FACS(pan, c0, c1, c2, c3)
                v = fnma4(v, c0, P0); v = fnma4(v, c1, P1);
                v = fnma4(v, c2, P2); v = fnma4(v, c3, P3);
                LD4(i, g) = v;
            }
        }
#undef FACS
        __syncthreads();
    }

    // ---- epilogue: parallel logf over diag, shuffle reduce (waves 0-1 only)
    float lsum = 0.0f;
    int   lneg = 0;
    if (tid < BLK) {
        const float d = diag[tid];
        lsum = logf(fabsf(d));                   // d==0 -> -inf -> caught below
        lneg = (d < 0.0f) ? 1 : 0;
    }
    if (tid < 128) {
        for (int off = 32; off > 0; off >>= 1) {
            lsum += __shfl_down(lsum, off);
            lneg += __shfl_down(lneg, off);
        }
        if ((tid & 63) == 0) { ps[tid >> 6] = lsum; pn[tid >> 6] = lneg; }
    }
    __syncthreads();
    if (tid == 0) {
        float ld = ps[0] + ps[1];
        const int n = pn[0] + pn[1];
        if ((n & 1) || !isfinite(ld)) ld = __int_as_float(0x7fc00000);  // NaN
        out[1 + f] = ld;
        atomicAdd(out, ld);   // out[0] zeroed via memset before launch; NaN propagates
    }
}

extern "C" void kernel_launch(void* const* d_in, const int* in_sizes, int n_in,
                              void* d_out, int out_size, void* d_ws, size_t ws_size,
                              hipStream_t stream) {
    const float* w = (const float*)d_in[0];   // weights (12800,) f32
    const float* L = (const float*)d_in[1];   // L_kernel (12800,12800) f32
    float* out = (float*)d_out;               // [0]=sum, [1..128]=logdets
    hipMemsetAsync(d_out, 0, sizeof(float), stream);   // zero the atomic accumulator
    lu_logdet_kernel<<<NF, NT, 0, stream>>>(w, L, out);
}